// Round 3
// baseline (8540.996 us; speedup 1.0000x reference)
//
#include <hip/hip_runtime.h>

#define N_PTS 65536
#define DIM   1024
#define NCLS  256
#define NITER 25

typedef __attribute__((ext_vector_type(8)))  short short8;
typedef __attribute__((ext_vector_type(16))) float f32x16;

// ---- RNE float -> bf16 split helper ------------------------------------------
__device__ __forceinline__ unsigned short bf_split(float x, float& rem) {
    unsigned u = __float_as_uint(x);
    unsigned b = (u + 0x7fffu + ((u >> 16) & 1u)) & 0xffff0000u;
    rem = x - __uint_as_float(b);
    return (unsigned short)(b >> 16);
}
__device__ __forceinline__ unsigned short bf_rne(float x) {
    unsigned u = __float_as_uint(x);
    return (unsigned short)((u + 0x7fffu + ((u >> 16) & 1u)) >> 16);
}

// ---------------- argmax(logits) -> init labels (first-max tie-break) ---------
__global__ void k_argmax(const float* __restrict__ logits, int* __restrict__ labels) {
    int row  = blockIdx.x * 4 + (threadIdx.x >> 6);
    int lane = threadIdx.x & 63;
    float4 v = reinterpret_cast<const float4*>(logits + (size_t)row * NCLS)[lane];
    float bv = v.x; int bi = lane * 4;
    if (v.y > bv) { bv = v.y; bi = lane * 4 + 1; }
    if (v.z > bv) { bv = v.z; bi = lane * 4 + 2; }
    if (v.w > bv) { bv = v.w; bi = lane * 4 + 3; }
    #pragma unroll
    for (int off = 32; off >= 1; off >>= 1) {
        float ov = __shfl_down(bv, off, 64);
        int   oi = __shfl_down(bi, off, 64);
        if (ov > bv || (ov == bv && oi < bi)) { bv = ov; bi = oi; }
    }
    if (lane == 0) labels[row] = bi;
}

// ---------------- label histogram (init path only) ----------------------------
__global__ void k_hist(const int* __restrict__ labels, int* __restrict__ counts) {
    __shared__ int h[NCLS];
    h[threadIdx.x] = 0;
    __syncthreads();
    for (int i = blockIdx.x * blockDim.x + threadIdx.x; i < N_PTS;
         i += gridDim.x * blockDim.x)
        atomicAdd(&h[labels[i]], 1);
    __syncthreads();
    int v = h[threadIdx.x];
    if (v) atomicAdd(&counts[threadIdx.x], v);
}

// ---------------- segment-sum accumulate (fixed-point, deterministic) ---------
__global__ __launch_bounds__(512) void k_accum(const float* __restrict__ feat,
                                               const int* __restrict__ labels,
                                               float* __restrict__ partials) {
    __shared__ unsigned long long s[NCLS * 32];
    int tid = threadIdx.x;
    for (int i = tid; i < NCLS * 32; i += 512) s[i] = 0ull;
    __syncthreads();
    int slice = blockIdx.x;
    int chunk = blockIdx.y;
    int w = tid >> 6, l = tid & 63;
    int sub = l >> 3;
    int dq  = l & 7;
    const size_t dbase = (size_t)slice * 32 + dq * 4;
    for (int step = 0; step < 128; ++step) {
        int p = chunk * 8192 + step * 64 + w * 8 + sub;
        int c = labels[p];
        float4 f = *reinterpret_cast<const float4*>(feat + (size_t)p * DIM + dbase);
        unsigned long long* dst = &s[c * 32 + dq * 4];
        atomicAdd(dst + 0, (unsigned long long)__double2ll_rn((double)f.x * 16777216.0));
        atomicAdd(dst + 1, (unsigned long long)__double2ll_rn((double)f.y * 16777216.0));
        atomicAdd(dst + 2, (unsigned long long)__double2ll_rn((double)f.z * 16777216.0));
        atomicAdd(dst + 3, (unsigned long long)__double2ll_rn((double)f.w * 16777216.0));
    }
    __syncthreads();
    float* out = partials + (size_t)chunk * NCLS * DIM;
    for (int i = tid; i < NCLS * 32; i += 512) {
        int c = i >> 5, d = i & 31;
        out[(size_t)c * DIM + slice * 32 + d] =
            (float)((double)(long long)s[i] * (1.0 / 16777216.0));
    }
}

// ---------------- reduce chunks, divide, keep prev if empty -------------------
__global__ void k_finalize(const float* __restrict__ partials,
                           const int* __restrict__ counts,
                           float* __restrict__ centroids) {
    int idx = blockIdx.x * blockDim.x + threadIdx.x;
    int c = idx >> 8;
    size_t off = (size_t)idx * 4;
    float4 sum = make_float4(0.f, 0.f, 0.f, 0.f);
    for (int ch = 0; ch < 8; ++ch) {
        float4 p = *reinterpret_cast<const float4*>(partials + (size_t)ch * NCLS * DIM + off);
        sum.x += p.x; sum.y += p.y; sum.z += p.z; sum.w += p.w;
    }
    int cnt = counts[c];
    float4 outv;
    if (cnt > 0) {
        float fc = (float)cnt;
        outv = make_float4(sum.x / fc, sum.y / fc, sum.z / fc, sum.w / fc);
    } else {
        outv = *reinterpret_cast<const float4*>(centroids + off);
    }
    *reinterpret_cast<float4*>(centroids + off) = outv;
}

// ---------------- centroid squared norms --------------------------------------
__global__ void k_norms(const float* __restrict__ centroids, float* __restrict__ norms) {
    int c = blockIdx.x;
    int t = threadIdx.x;
    float4 v = reinterpret_cast<const float4*>(centroids + (size_t)c * DIM)[t];
    float s = v.x * v.x + v.y * v.y + v.z * v.z + v.w * v.w;
    __shared__ float red[4];
    #pragma unroll
    for (int off = 32; off >= 1; off >>= 1) s += __shfl_down(s, off, 64);
    if ((t & 63) == 0) red[t >> 6] = s;
    __syncthreads();
    if (t == 0) norms[c] = red[0] + red[1] + red[2] + red[3];
}

// ---------------- centroid bf16x3 split, MFMA-fragment-ordered ----------------
// Bs layout (ushort): [kc 32][plane 3][ntile 8][kh 2][lane 64][j 8]
__global__ void k_splitB(const float* __restrict__ cent, unsigned short* __restrict__ Bs) {
    int lin = blockIdx.x * 256 + threadIdx.x;
    int n = lin & 255, kg = lin >> 8;
    int k = kg * 8;
    int kc = kg >> 2, kh = (kg >> 1) & 1, jg = kg & 1;
    int nt = n >> 5, lane = (n & 31) + 32 * jg;
    const float* src = cent + (size_t)n * DIM + k;
    unsigned short hi[8], mi[8], lo[8];
    #pragma unroll
    for (int j = 0; j < 8; ++j) {
        float r1, r2;
        hi[j] = bf_split(src[j], r1);
        mi[j] = bf_split(r1, r2);
        lo[j] = bf_rne(r2);
    }
    #pragma unroll
    for (int p = 0; p < 3; ++p) {
        size_t base = ((((size_t)kc * 3 + p) * 8 + nt) * 2 + kh) * 512 + (size_t)lane * 8;
        const unsigned short* srcp = (p == 0) ? hi : (p == 1) ? mi : lo;
        uint4 pack = *reinterpret_cast<const uint4*>(srcp);
        *reinterpret_cast<uint4*>(Bs + base) = pack;
    }
}

// ---------------- assign: barrier-free bf16x3 MFMA GEMM + fused argmin --------
// block 256 (4 waves), tile M=128 (32/wave) x N=128 (blockIdx.y half).
// A built in-register from the lane's own global floats. B fragments read
// straight from global (1.5 MB, L1/L2-resident, identical across blocks).
// ZERO __syncthreads, zero LDS -> no vmcnt(0) drain points.
__global__ __launch_bounds__(256, 3) void k_assign(
        const float* __restrict__ feat, const unsigned short* __restrict__ Bs,
        const float* __restrict__ norms, unsigned long long* __restrict__ part) {
    int tid = threadIdx.x, w = tid >> 6, l = tid & 63;
    int cn = l & 31, jg = l >> 5;
    int p0 = blockIdx.x * 128;
    int nh = blockIdx.y;
    int n0 = nh * 128;

    f32x16 acc[4];
    #pragma unroll
    for (int t = 0; t < 4; ++t)
        #pragma unroll
        for (int i = 0; i < 16; ++i) acc[t][i] = 0.f;

    const float* arow = feat + (size_t)(p0 + w * 32 + cn) * DIM + jg * 8;
    // per-lane B fragment base: + nh*4096 + l*8 (ushort units)
    const unsigned short* bbase = Bs + (size_t)nh * 4096 + (size_t)l * 8;

    // prefetch A for kc=0
    float4 ga0 = *reinterpret_cast<const float4*>(arow + 0);
    float4 ga1 = *reinterpret_cast<const float4*>(arow + 4);
    float4 ga2 = *reinterpret_cast<const float4*>(arow + 16);
    float4 ga3 = *reinterpret_cast<const float4*>(arow + 20);

    for (int kc = 0; kc < 32; ++kc) {
        float xs[16] = {ga0.x, ga0.y, ga0.z, ga0.w, ga1.x, ga1.y, ga1.z, ga1.w,
                        ga2.x, ga2.y, ga2.z, ga2.w, ga3.x, ga3.y, ga3.z, ga3.w};
        if (kc < 31) {       // prefetch next kc's A a full iteration ahead
            int k1 = (kc + 1) * 32;
            ga0 = *reinterpret_cast<const float4*>(arow + k1);
            ga1 = *reinterpret_cast<const float4*>(arow + k1 + 4);
            ga2 = *reinterpret_cast<const float4*>(arow + k1 + 16);
            ga3 = *reinterpret_cast<const float4*>(arow + k1 + 20);
        }
        // split A in-register -> 6 fragments
        union { short8 v; unsigned short u[8]; } af[2][3];
        #pragma unroll
        for (int kh = 0; kh < 2; ++kh)
            #pragma unroll
            for (int j = 0; j < 8; ++j) {
                float r1, r2;
                af[kh][0].u[j] = bf_split(xs[kh * 8 + j], r1);
                af[kh][1].u[j] = bf_split(r1, r2);
                af[kh][2].u[j] = bf_rne(r2);
            }
        const unsigned short* bkc = bbase + (size_t)kc * 24576;
        // 6 split-product pairings: (h,h)(m,h)(l,h)(h,m)(m,m)(h,l)
        #pragma unroll
        for (int q = 0; q < 3; ++q) {
            short8 bq[8];
            #pragma unroll
            for (int ntl = 0; ntl < 4; ++ntl)
                #pragma unroll
                for (int kh = 0; kh < 2; ++kh)
                    bq[ntl * 2 + kh] = *reinterpret_cast<const short8*>(
                        bkc + q * 8192 + ntl * 1024 + kh * 512);
            #pragma unroll
            for (int ntl = 0; ntl < 4; ++ntl)
                #pragma unroll
                for (int kh = 0; kh < 2; ++kh) {
                    short8 bf = bq[ntl * 2 + kh];
                    acc[ntl] = __builtin_amdgcn_mfma_f32_32x32x16_bf16(
                        af[kh][0].v, bf, acc[ntl], 0, 0, 0);
                    if (q < 2)
                        acc[ntl] = __builtin_amdgcn_mfma_f32_32x32x16_bf16(
                            af[kh][1].v, bf, acc[ntl], 0, 0, 0);
                    if (q == 0)
                        acc[ntl] = __builtin_amdgcn_mfma_f32_32x32x16_bf16(
                            af[kh][2].v, bf, acc[ntl], 0, 0, 0);
                }
        }
    }

    // epilogue: scores = ||mu||^2 - 2*dot ; argmin, first-index tie-break
    float nrm[4];
    #pragma unroll
    for (int ntl = 0; ntl < 4; ++ntl) nrm[ntl] = norms[n0 + ntl * 32 + cn];
    #pragma unroll
    for (int r = 0; r < 16; ++r) {
        unsigned long long key = ~0ull;
        #pragma unroll
        for (int ntl = 0; ntl < 4; ++ntl) {
            float s = nrm[ntl] - 2.0f * acc[ntl][r];
            unsigned u = __float_as_uint(s);
            u = (u & 0x80000000u) ? ~u : (u | 0x80000000u);
            unsigned long long kk =
                ((unsigned long long)u << 32) | (unsigned)(n0 + ntl * 32 + cn);
            key = (kk < key) ? kk : key;
        }
        #pragma unroll
        for (int off = 16; off >= 1; off >>= 1) {
            unsigned long long ok = __shfl_xor(key, off, 64);
            key = (ok < key) ? ok : key;
        }
        if (cn == 0) {
            int m = p0 + w * 32 + (r & 3) + 8 * (r >> 2) + 4 * jg;
            part[(size_t)nh * N_PTS + m] = key;
        }
    }
}

// ---------------- combine N-halves, extract labels, fused histogram -----------
__global__ void k_combine(const unsigned long long* __restrict__ part,
                          int* __restrict__ labels, int* __restrict__ counts) {
    __shared__ int h[NCLS];
    h[threadIdx.x] = 0;
    __syncthreads();
    int i = blockIdx.x * 256 + threadIdx.x;
    unsigned long long a = part[i], b = part[N_PTS + i];
    unsigned long long k = (b < a) ? b : a;
    int lab = (int)(k & 0xffffffffull);
    labels[i] = lab;
    atomicAdd(&h[lab], 1);
    __syncthreads();
    int v = h[threadIdx.x];
    if (v) atomicAdd(&counts[threadIdx.x], v);
}

// ---------------- driver -------------------------------------------------------
extern "C" void kernel_launch(void* const* d_in, const int* in_sizes, int n_in,
                              void* d_out, int out_size, void* d_ws, size_t ws_size,
                              hipStream_t stream) {
    const float* feat   = (const float*)d_in[0];
    const float* logits = (const float*)d_in[1];
    int* out_labels = (int*)d_out;

    char* ws = (char*)d_ws;
    float* centroids            = (float*)ws;                        // 1 MB
    float* partials             = (float*)(ws + 0x100000);           // 8 MB
    float* norms                = (float*)(ws + 0x900000);           // 1 KB
    int*   counts               = (int*)  (ws + 0x901000);           // 1 KB
    int*   labels               = (int*)  (ws + 0x902000);           // 256 KB
    unsigned short* Bs          = (unsigned short*)(ws + 0x950000);  // 1.5 MB
    unsigned long long* part    = (unsigned long long*)(ws + 0xAD0000); // 1 MB

    // ---- init: labels from argmax(logits); centroids from label centers
    k_argmax<<<N_PTS / 4, 256, 0, stream>>>(logits, labels);
    hipMemsetAsync(centroids, 0, (size_t)NCLS * DIM * sizeof(float), stream);
    hipMemsetAsync(counts, 0, NCLS * sizeof(int), stream);
    k_hist<<<64, 256, 0, stream>>>(labels, counts);
    k_accum<<<dim3(32, 8), 512, 0, stream>>>(feat, labels, partials);
    k_finalize<<<256, 256, 0, stream>>>(partials, counts, centroids);

    // ---- 25 Lloyd iterations
    for (int it = 0; it < NITER; ++it) {
        k_norms<<<NCLS, 256, 0, stream>>>(centroids, norms);
        k_splitB<<<128, 256, 0, stream>>>(centroids, Bs);
        k_assign<<<dim3(N_PTS / 128, 2), 256, 0, stream>>>(feat, Bs, norms, part);
        hipMemsetAsync(counts, 0, NCLS * sizeof(int), stream);
        k_combine<<<N_PTS / 256, 256, 0, stream>>>(part, labels, counts);
        k_accum<<<dim3(32, 8), 512, 0, stream>>>(feat, labels, partials);
        k_finalize<<<256, 256, 0, stream>>>(partials, counts, centroids);
    }

    // ---- final assignment -> output labels (int32)
    k_norms<<<NCLS, 256, 0, stream>>>(centroids, norms);
    k_splitB<<<128, 256, 0, stream>>>(centroids, Bs);
    k_assign<<<dim3(N_PTS / 128, 2), 256, 0, stream>>>(feat, Bs, norms, part);
    hipMemsetAsync(counts, 0, NCLS * sizeof(int), stream);
    k_combine<<<N_PTS / 256, 256, 0, stream>>>(part, out_labels, counts);
}